// Round 6
// baseline (1143.464 us; speedup 1.0000x reference)
//
#include <hip/hip_runtime.h>
#include <hip/hip_bf16.h>

#define B_ 512
#define T_ 49
#define I_ 96
#define H_ 1024
#define NBLK 256

typedef __attribute__((ext_vector_type(4))) float f32x4;
typedef __attribute__((ext_vector_type(8))) short s16x8;

__device__ __forceinline__ unsigned short f2bf(float f) {
    unsigned int u = __float_as_uint(f);
    unsigned int r = (u + 0x7FFFu + ((u >> 16) & 1u)) >> 16;
    return (unsigned short)r;
}
__device__ __forceinline__ float sigmoidf_(float x) {
    return 1.0f / (1.0f + __expf(-x));
}
__device__ __forceinline__ float tanhf_(float x) {
    return 1.0f - 2.0f / (__expf(2.0f * x) + 1.0f);
}

__device__ __forceinline__ void gload_lds16(const unsigned short* g, unsigned short* l) {
    __builtin_amdgcn_global_load_lds(
        (const __attribute__((address_space(1))) void*)g,
        (__attribute__((address_space(3))) void*)l, 16, 0, 0);
}

// ------------- quantize fp32 -> bf16; x transposed to [t][b][i];
// ------------- also zeroes the barrier counters (every call) -------------
__global__ void quantize_kernel(const float* __restrict__ Whh,
                                const float* __restrict__ Wih,
                                const float* __restrict__ x,
                                unsigned short* __restrict__ Whh_bf,
                                unsigned short* __restrict__ Wih_bf,
                                unsigned short* __restrict__ xT_bf,
                                unsigned int* __restrict__ cnt) {
    const long stride = (long)gridDim.x * blockDim.x;
    const long idx = (long)blockIdx.x * blockDim.x + threadIdx.x;

    if (blockIdx.x == 0 && threadIdx.x < T_) cnt[threadIdx.x] = 0;

    const long nWhh4 = (long)3 * H_ * H_ / 4;
    const long nWih4 = (long)3 * H_ * I_ / 4;
    const long nX4   = (long)B_ * T_ * I_ / 4;

    for (long i = idx; i < nWhh4; i += stride) {
        float4 v = ((const float4*)Whh)[i];
        ushort4 o; o.x = f2bf(v.x); o.y = f2bf(v.y); o.z = f2bf(v.z); o.w = f2bf(v.w);
        ((ushort4*)Whh_bf)[i] = o;
    }
    for (long i = idx; i < nWih4; i += stride) {
        float4 v = ((const float4*)Wih)[i];
        ushort4 o; o.x = f2bf(v.x); o.y = f2bf(v.y); o.z = f2bf(v.z); o.w = f2bf(v.w);
        ((ushort4*)Wih_bf)[i] = o;
    }
    for (long i = idx; i < nX4; i += stride) {
        float4 v = ((const float4*)x)[i];
        ushort4 o; o.x = f2bf(v.x); o.y = f2bf(v.y); o.z = f2bf(v.z); o.w = f2bf(v.w);
        const long e = i * 4;                 // flat elem idx in [b][t][i]
        const int b  = (int)(e / (T_ * I_));
        const int rm = (int)(e - (long)b * (T_ * I_));
        const int tt = rm / I_;
        const int ii = rm - tt * I_;
        ((ushort4*)xT_bf)[(((long)tt * B_ + b) * I_ + ii) >> 2] = o;
    }
}

// ---------------- persistent GRU (v2): all 49 steps, one launch ----------------
// 256 blocks x 512 thr (8 waves = 4 mq x 2 kg), 1 block/CU (128 KiB LDS),
// cooperative launch (co-residency) but a HAND-ROLLED per-step barrier:
//   arrive: atomic_fetch_add(RELEASE, AGENT)  -> writeback of dirty h lines
//   spin:   RELAXED atomic loads + s_sleep    -> no per-poll invalidate
//   done:   one ACQUIRE load                  -> single L1/L2 inv per step
// W_hh slice [3][16][1024] loaded into LDS ONCE (XOR-swizzled source, linear
// dest, rule #21); ds_read applies byte_off ^= (row&7)<<4. h blend state in
// registers (kg0). h crosses blocks as bf16 only, via L3.
__global__ __launch_bounds__(512, 2)
void gru_persist2(const unsigned short* __restrict__ Whh_bf,
                  const unsigned short* __restrict__ Wih_bf,
                  const unsigned short* __restrict__ xT_bf,
                  const float* __restrict__ b_ih,
                  const float* __restrict__ b_hh,
                  unsigned short* __restrict__ hbf0,
                  unsigned short* __restrict__ hbf1,
                  float* __restrict__ out,
                  unsigned int* __restrict__ cnt)
{
    __shared__ __align__(16) unsigned short Wl[3 * 16 * 1024]; // 96 KiB
    __shared__ __align__(16) f32x4 Red[4 * 8 * 64];            // 32 KiB

    const int tid = threadIdx.x;
    const int w   = tid >> 6;
    const int l   = tid & 63;
    const int l15 = l & 15;
    const int l4  = l >> 4;
    const int mq  = w >> 1;      // 0..3 : 32-row slice
    const int kg  = w & 1;       // 0..1 : K half

    const int bid  = blockIdx.x;
    const int xcd  = bid & 7;
    const int r_   = bid >> 3;
    const int blkb = r_ & 3;              // 4 b-tiles of 128
    const int blkj = xcd * 8 + (r_ >> 2); // 64 j-tiles of 16, XCD-grouped
    const int b0   = blkb * 128;
    const int j0   = blkj * 16;
    const int jg   = j0 + l15;
    const int brow = b0 + mq * 32;

    // ---- one-time: W_hh slice -> LDS (async DMA, swizzled source) ----
#pragma unroll
    for (int i = 0; i < 12; ++i) {
        const int row  = w * 6 + (i >> 1);    // 0..47 (g*16+jj)
        const int half = i & 1;
        const int g    = row >> 4;
        const int jj   = row & 15;
        const unsigned short* src = Whh_bf
            + ((long)g * H_ + j0 + jj) * H_ + half * 512
            + ((l ^ (jj & 7)) * 8);
        unsigned short* dst = Wl + (g * 16 + jj) * 1024 + half * 512;
        gload_lds16(src, dst);
    }

    // ---- loop-invariant scalars/pointers ----
    const float bR   = b_ih[jg] + b_hh[jg];
    const float bZ   = b_ih[H_ + jg] + b_hh[H_ + jg];
    const float bihN = b_ih[2 * H_ + jg];
    const float bhhN = b_hh[2 * H_ + jg];

    const unsigned short* Vr = Wih_bf + (long)(j0 + l15) * I_ + l4 * 8;
    const unsigned short* Vz = Wih_bf + (long)(H_ + j0 + l15) * I_ + l4 * 8;
    const unsigned short* Vn = Wih_bf + (long)(2 * H_ + j0 + l15) * I_ + l4 * 8;

    const unsigned short* Wr = Wl + (0 * 16 + l15) * 1024;
    const unsigned short* Wz = Wl + (1 * 16 + l15) * 1024;
    const unsigned short* Wn = Wl + (2 * 16 + l15) * 1024;
    const int swz   = (l15 & 7) << 3;            // XOR in shorts (=<<4 bytes)
    const int kbase = kg * 512 + l4 * 8;

    float hreg[2][4] = {{0.f,0.f,0.f,0.f},{0.f,0.f,0.f,0.f}};  // kg0 h state

    for (int t = 0; t < T_; ++t) {
        const unsigned short* hin  = (t & 1) ? hbf1 : hbf0;  // written at t-1
        unsigned short*       hout = (t & 1) ? hbf0 : hbf1;

        f32x4 accR[2], accZ[2], accNh[2], accNi[2];
#pragma unroll
        for (int m = 0; m < 2; ++m) {
            accR[m]  = (f32x4){0.f, 0.f, 0.f, 0.f};
            accZ[m]  = (f32x4){0.f, 0.f, 0.f, 0.f};
            accNh[m] = (f32x4){0.f, 0.f, 0.f, 0.f};
            accNi[m] = (f32x4){0.f, 0.f, 0.f, 0.f};
        }

        // ---- kg1: input GEMM gi = x_t @ W_ih^T (K=96) ----
        if (kg == 1) {
            const unsigned short* Ax0 = xT_bf + ((long)t * B_ + brow + l15) * I_ + l4 * 8;
            const unsigned short* Ax1 = Ax0 + 16 * I_;
#pragma unroll
            for (int ks = 0; ks < 3; ++ks) {
                s16x8 a0 = *(const s16x8*)(Ax0 + ks * 32);
                s16x8 a1 = *(const s16x8*)(Ax1 + ks * 32);
                s16x8 br = *(const s16x8*)(Vr + ks * 32);
                s16x8 bz = *(const s16x8*)(Vz + ks * 32);
                s16x8 bn = *(const s16x8*)(Vn + ks * 32);
                accR[0]  = __builtin_amdgcn_mfma_f32_16x16x32_bf16(a0, br, accR[0], 0, 0, 0);
                accR[1]  = __builtin_amdgcn_mfma_f32_16x16x32_bf16(a1, br, accR[1], 0, 0, 0);
                accZ[0]  = __builtin_amdgcn_mfma_f32_16x16x32_bf16(a0, bz, accZ[0], 0, 0, 0);
                accZ[1]  = __builtin_amdgcn_mfma_f32_16x16x32_bf16(a1, bz, accZ[1], 0, 0, 0);
                accNi[0] = __builtin_amdgcn_mfma_f32_16x16x32_bf16(a0, bn, accNi[0], 0, 0, 0);
                accNi[1] = __builtin_amdgcn_mfma_f32_16x16x32_bf16(a1, bn, accNi[1], 0, 0, 0);
            }
        }

        // ---- recurrent GEMM: wave's K-half; W from LDS, A all-upfront ----
        if (t > 0) {
            const unsigned short* Ab0 = hin + (long)(brow + l15) * H_ + kg * 512 + l4 * 8;
            const unsigned short* Ab1 = Ab0 + 16 * H_;

            s16x8 Af[8][4];
#pragma unroll
            for (int kk = 0; kk < 8; ++kk) {
                Af[kk][0] = *(const s16x8*)(Ab0 + kk * 64);
                Af[kk][1] = *(const s16x8*)(Ab0 + kk * 64 + 32);
                Af[kk][2] = *(const s16x8*)(Ab1 + kk * 64);
                Af[kk][3] = *(const s16x8*)(Ab1 + kk * 64 + 32);
            }

#pragma unroll
            for (int kk = 0; kk < 8; ++kk) {
#pragma unroll
                for (int q = 0; q < 2; ++q) {
                    const int off = ((kbase + (kk * 2 + q) * 32) ^ swz);
                    s16x8 br = *(const s16x8*)(Wr + off);
                    s16x8 bz = *(const s16x8*)(Wz + off);
                    s16x8 bn = *(const s16x8*)(Wn + off);
                    s16x8 a0 = Af[kk][q];
                    s16x8 a1 = Af[kk][q + 2];
                    accR[0]  = __builtin_amdgcn_mfma_f32_16x16x32_bf16(a0, br, accR[0], 0, 0, 0);
                    accR[1]  = __builtin_amdgcn_mfma_f32_16x16x32_bf16(a1, br, accR[1], 0, 0, 0);
                    accZ[0]  = __builtin_amdgcn_mfma_f32_16x16x32_bf16(a0, bz, accZ[0], 0, 0, 0);
                    accZ[1]  = __builtin_amdgcn_mfma_f32_16x16x32_bf16(a1, bz, accZ[1], 0, 0, 0);
                    accNh[0] = __builtin_amdgcn_mfma_f32_16x16x32_bf16(a0, bn, accNh[0], 0, 0, 0);
                    accNh[1] = __builtin_amdgcn_mfma_f32_16x16x32_bf16(a1, bn, accNh[1], 0, 0, 0);
                }
            }
        }

        // ---- merge kg partials via LDS (also drains one-time W DMA at t=0) ----
        __syncthreads();
        if (kg == 1) {
            f32x4* dst = &Red[(mq * 8) * 64 + l];
            dst[0 * 64] = accR[0];  dst[1 * 64] = accR[1];
            dst[2 * 64] = accZ[0];  dst[3 * 64] = accZ[1];
            dst[4 * 64] = accNh[0]; dst[5 * 64] = accNh[1];
            dst[6 * 64] = accNi[0]; dst[7 * 64] = accNi[1];
        }
        __syncthreads();

        if (kg == 0) {
            const f32x4* srcp = &Red[(mq * 8) * 64 + l];
            accR[0]  += srcp[0 * 64]; accR[1]  += srcp[1 * 64];
            accZ[0]  += srcp[2 * 64]; accZ[1]  += srcp[3 * 64];
            accNh[0] += srcp[4 * 64]; accNh[1] += srcp[5 * 64];
            accNi[0] += srcp[6 * 64]; accNi[1] += srcp[7 * 64];

#pragma unroll
            for (int f = 0; f < 2; ++f) {
#pragma unroll
                for (int r = 0; r < 4; ++r) {
                    const float rg = sigmoidf_(accR[f][r] + bR);
                    const float zg = sigmoidf_(accZ[f][r] + bZ);
                    const float ng = tanhf_(accNi[f][r] + bihN + rg * (accNh[f][r] + bhhN));
                    hreg[f][r] = (1.0f - zg) * ng + zg * hreg[f][r];
                    const long off = (long)(brow + f * 16 + l4 * 4 + r) * H_ + jg;
                    if (t < T_ - 1) hout[off] = f2bf(hreg[f][r]);
                    else            out[off]  = hreg[f][r];
                }
            }
        }

        // ---- lean device-wide barrier (not after last step) ----
        if (t < T_ - 1) {
            __syncthreads();   // all waves' h stores drained (vmcnt 0 at barrier)
            if (tid == 0) {
                __hip_atomic_fetch_add(&cnt[t], 1u, __ATOMIC_RELEASE,
                                       __HIP_MEMORY_SCOPE_AGENT);
                while (__hip_atomic_load(&cnt[t], __ATOMIC_RELAXED,
                                         __HIP_MEMORY_SCOPE_AGENT) < NBLK)
                    __builtin_amdgcn_s_sleep(2);
                (void)__hip_atomic_load(&cnt[t], __ATOMIC_ACQUIRE,
                                        __HIP_MEMORY_SCOPE_AGENT);
            }
            __syncthreads();
        }
    }
}

extern "C" void kernel_launch(void* const* d_in, const int* in_sizes, int n_in,
                              void* d_out, int out_size, void* d_ws, size_t ws_size,
                              hipStream_t stream) {
    const float* enc_in = (const float*)d_in[0];
    const float* W_ih   = (const float*)d_in[1];
    const float* W_hh   = (const float*)d_in[2];
    const float* b_ih   = (const float*)d_in[3];
    const float* b_hh   = (const float*)d_in[4];
    float* out = (float*)d_out;

    char* ws = (char*)d_ws;
    unsigned short* Whh_bf = (unsigned short*)(ws);             // 6,291,456 B
    unsigned short* Wih_bf = (unsigned short*)(ws + 6291456);   //   589,824 B
    unsigned short* xT_bf  = (unsigned short*)(ws + 6881280);   // 4,816,896 B
    unsigned short* hbf0   = (unsigned short*)(ws + 11698176);  // 1,048,576 B
    unsigned short* hbf1   = (unsigned short*)(ws + 12746752);  // 1,048,576 B
    unsigned int*   cnt    = (unsigned int*)(ws + 13795328);    //       196 B

    quantize_kernel<<<dim3(1024), dim3(256), 0, stream>>>(W_hh, W_ih, enc_in,
                                                          Whh_bf, Wih_bf, xT_bf, cnt);

    void* args[] = {(void*)&Whh_bf, (void*)&Wih_bf, (void*)&xT_bf,
                    (void*)&b_ih, (void*)&b_hh,
                    (void*)&hbf0, (void*)&hbf1, (void*)&out, (void*)&cnt};
    hipLaunchCooperativeKernel((const void*)gru_persist2,
                               dim3(256), dim3(512), args, 0, stream);
}

// Round 7
// 817.008 us; speedup vs baseline: 1.3996x; 1.3996x over previous
//
#include <hip/hip_runtime.h>
#include <hip/hip_bf16.h>

#define B_ 512
#define T_ 49
#define I_ 96
#define H_ 1024
#define NBLK 256
#define NGRP 8
#define GSZ  32   /* blocks per arrival group */

typedef __attribute__((ext_vector_type(4))) float f32x4;
typedef __attribute__((ext_vector_type(8))) short s16x8;

__device__ __forceinline__ unsigned short f2bf(float f) {
    unsigned int u = __float_as_uint(f);
    unsigned int r = (u + 0x7FFFu + ((u >> 16) & 1u)) >> 16;
    return (unsigned short)r;
}
__device__ __forceinline__ float sigmoidf_(float x) {
    return 1.0f / (1.0f + __expf(-x));
}
__device__ __forceinline__ float tanhf_(float x) {
    return 1.0f - 2.0f / (__expf(2.0f * x) + 1.0f);
}

__device__ __forceinline__ void gload_lds16(const unsigned short* g, unsigned short* l) {
    __builtin_amdgcn_global_load_lds(
        (const __attribute__((address_space(1))) void*)g,
        (__attribute__((address_space(3))) void*)l, 16, 0, 0);
}

// ------------- quantize fp32 -> bf16; x transposed to [t][b][i];
// ------------- zeroes the barrier region (every call) -------------
__global__ void quantize_kernel(const float* __restrict__ Whh,
                                const float* __restrict__ Wih,
                                const float* __restrict__ x,
                                unsigned short* __restrict__ Whh_bf,
                                unsigned short* __restrict__ Wih_bf,
                                unsigned short* __restrict__ xT_bf,
                                unsigned int* __restrict__ bar) {
    const long stride = (long)gridDim.x * blockDim.x;
    const long idx = (long)blockIdx.x * blockDim.x + threadIdx.x;

    if (blockIdx.x == 0)
        for (int i = threadIdx.x; i < T_ * 10 * 64; i += 256) bar[i] = 0;

    const long nWhh4 = (long)3 * H_ * H_ / 4;
    const long nWih4 = (long)3 * H_ * I_ / 4;
    const long nX4   = (long)B_ * T_ * I_ / 4;

    for (long i = idx; i < nWhh4; i += stride) {
        float4 v = ((const float4*)Whh)[i];
        ushort4 o; o.x = f2bf(v.x); o.y = f2bf(v.y); o.z = f2bf(v.z); o.w = f2bf(v.w);
        ((ushort4*)Whh_bf)[i] = o;
    }
    for (long i = idx; i < nWih4; i += stride) {
        float4 v = ((const float4*)Wih)[i];
        ushort4 o; o.x = f2bf(v.x); o.y = f2bf(v.y); o.z = f2bf(v.z); o.w = f2bf(v.w);
        ((ushort4*)Wih_bf)[i] = o;
    }
    for (long i = idx; i < nX4; i += stride) {
        float4 v = ((const float4*)x)[i];
        ushort4 o; o.x = f2bf(v.x); o.y = f2bf(v.y); o.z = f2bf(v.z); o.w = f2bf(v.w);
        const long e = i * 4;                 // flat elem idx in [b][t][i]
        const int b  = (int)(e / (T_ * I_));
        const int rm = (int)(e - (long)b * (T_ * I_));
        const int tt = rm / I_;
        const int ii = rm - tt * I_;
        ((ushort4*)xT_bf)[(((long)tt * B_ + b) * I_ + ii) >> 2] = o;
    }
}

// ---------------- persistent GRU (v3) ----------------
// 256 blocks x 512 thr (8 waves, one 16-row m-slice each), 1 block/CU.
// Block tile 128b x 16j x 3g. W_hh + W_ih LDS-resident in 1KB k-step TILES:
// tile p holds, at byte offset p*1024 + lane*16, exactly lane's MFMA B-frag
// -> every ds_read_b128 is linear-per-lane = conflict-free. A-operand (h)
// global->reg ring-12 (covers ~600cy L3 latency). h blend state in regs.
// Hierarchical per-step barrier: 8 group counters (release-arrive) -> root
// -> flag; spin RELAXED on quiet flag line; one ACQUIRE per block.
__global__ __launch_bounds__(512)
void gru_persist3(const unsigned short* __restrict__ Whh_bf,
                  const unsigned short* __restrict__ Wih_bf,
                  const unsigned short* __restrict__ xT_bf,
                  const float* __restrict__ b_ih,
                  const float* __restrict__ b_hh,
                  unsigned short* __restrict__ hbf0,
                  unsigned short* __restrict__ hbf1,
                  float* __restrict__ out,
                  unsigned int* __restrict__ bar)
{
    // tiles: p in [0,96) = Whh (p = g*32 + ks); p in [96,105) = Wih (p = 96 + g*3 + ks)
    __shared__ __align__(16) unsigned short Wl[105 * 512];   // 107,520 B

    const int tid = threadIdx.x;
    const int w   = tid >> 6;
    const int l   = tid & 63;
    const int l15 = l & 15;
    const int l4  = l >> 4;

    const int bid  = blockIdx.x;
    const int xcd  = bid & 7;
    const int r_   = bid >> 3;
    const int blkb = r_ & 3;              // 4 b-tiles of 128
    const int blkj = xcd * 8 + (r_ >> 2); // 64 j-tiles of 16, XCD-grouped
    const int b0   = blkb * 128;
    const int j0   = blkj * 16;
    const int jg   = j0 + l15;
    const int brow = b0 + w * 16;         // wave's 16 b-rows
    const int grp  = bid >> 5;            // arrival group (8 x 32)

    // ---- one-time: W_hh + W_ih slices -> LDS tiles (async DMA) ----
    for (int p = w; p < 105; p += 8) {
        const unsigned short* src;
        if (p < 96) {
            const int g = p >> 5, ks = p & 31;
            src = Whh_bf + ((long)g * H_ + j0 + l15) * H_ + ks * 32 + l4 * 8;
        } else {
            const int q = p - 96, g = q / 3, ks = q - g * 3;
            src = Wih_bf + ((long)g * H_ + j0 + l15) * I_ + ks * 32 + l4 * 8;
        }
        gload_lds16(src, &Wl[p * 512]);   // dest wave-uniform; HW adds lane*16B
    }

    // ---- loop-invariant scalars ----
    const float bR   = b_ih[jg] + b_hh[jg];
    const float bZ   = b_ih[H_ + jg] + b_hh[H_ + jg];
    const float bihN = b_ih[2 * H_ + jg];
    const float bhhN = b_hh[2 * H_ + jg];

    float hreg[4] = {0.f, 0.f, 0.f, 0.f};

    __syncthreads();   // drains all waves' W DMA (vmcnt 0 at barrier)

    for (int t = 0; t < T_; ++t) {
        const unsigned short* hin  = (t & 1) ? hbf1 : hbf0;
        unsigned short*       hout = (t & 1) ? hbf0 : hbf1;

        f32x4 accR  = (f32x4){0.f, 0.f, 0.f, 0.f};
        f32x4 accZ  = (f32x4){0.f, 0.f, 0.f, 0.f};
        f32x4 accNi = (f32x4){0.f, 0.f, 0.f, 0.f};
        f32x4 accNh = (f32x4){0.f, 0.f, 0.f, 0.f};

        // ---- input GEMM: gi = x_t @ W_ih^T (K=96, Wih tiles from LDS) ----
        {
            const unsigned short* Ax = xT_bf + ((long)t * B_ + brow + l15) * I_ + l4 * 8;
#pragma unroll
            for (int ks = 0; ks < 3; ++ks) {
                s16x8 a  = *(const s16x8*)(Ax + ks * 32);
                const unsigned short* wt = &Wl[(96 + ks) * 512 + l * 8];
                s16x8 br = *(const s16x8*)(wt);
                s16x8 bz = *(const s16x8*)(wt + 3 * 512);
                s16x8 bn = *(const s16x8*)(wt + 6 * 512);
                accR  = __builtin_amdgcn_mfma_f32_16x16x32_bf16(a, br, accR, 0, 0, 0);
                accZ  = __builtin_amdgcn_mfma_f32_16x16x32_bf16(a, bz, accZ, 0, 0, 0);
                accNi = __builtin_amdgcn_mfma_f32_16x16x32_bf16(a, bn, accNi, 0, 0, 0);
            }
        }

        // ---- recurrent GEMM: gh = h @ W_hh^T (K=1024, A ring-12 from global) ----
        if (t > 0) {
            const unsigned short* Ab = hin + (long)(brow + l15) * H_ + l4 * 8;
            s16x8 ar[12];
#pragma unroll
            for (int p = 0; p < 12; ++p)
                ar[p] = *(const s16x8*)(Ab + p * 32);
#pragma unroll
            for (int ks = 0; ks < 32; ++ks) {
                const int slot = ks % 12;
                s16x8 a = ar[slot];
                if (ks < 20)
                    ar[slot] = *(const s16x8*)(Ab + (ks + 12) * 32);
                const unsigned short* wt = &Wl[ks * 512 + l * 8];
                s16x8 br = *(const s16x8*)(wt);
                s16x8 bz = *(const s16x8*)(wt + 32 * 512);
                s16x8 bn = *(const s16x8*)(wt + 64 * 512);
                accR  = __builtin_amdgcn_mfma_f32_16x16x32_bf16(a, br, accR, 0, 0, 0);
                accZ  = __builtin_amdgcn_mfma_f32_16x16x32_bf16(a, bz, accZ, 0, 0, 0);
                accNh = __builtin_amdgcn_mfma_f32_16x16x32_bf16(a, bn, accNh, 0, 0, 0);
            }
        }

        // ---- epilogue: gates + blend; h state stays in registers ----
#pragma unroll
        for (int r = 0; r < 4; ++r) {
            const float rg = sigmoidf_(accR[r] + bR);
            const float zg = sigmoidf_(accZ[r] + bZ);
            const float ng = tanhf_(accNi[r] + bihN + rg * (accNh[r] + bhhN));
            hreg[r] = (1.0f - zg) * ng + zg * hreg[r];
            const long off = (long)(brow + l4 * 4 + r) * H_ + jg;
            if (t < T_ - 1) hout[off] = f2bf(hreg[r]);
            else            out[off]  = hreg[r];
        }

        // ---- hierarchical device barrier (not after last step) ----
        if (t < T_ - 1) {
            __syncthreads();   // all waves' h stores drained to L2
            if (tid == 0) {
                unsigned int* gcnt = &bar[(t * 10 + grp) * 64];
                unsigned int* root = &bar[(t * 10 + 8) * 64];
                unsigned int* flag = &bar[(t * 10 + 9) * 64];
                // release-arrive: flushes this block's XCD L2 (every block must)
                unsigned int old = __hip_atomic_fetch_add(gcnt, 1u, __ATOMIC_RELEASE,
                                                          __HIP_MEMORY_SCOPE_AGENT);
                if (old == GSZ - 1) {
                    unsigned int o2 = __hip_atomic_fetch_add(root, 1u, __ATOMIC_RELAXED,
                                                             __HIP_MEMORY_SCOPE_AGENT);
                    if (o2 == NGRP - 1)
                        __hip_atomic_store(flag, 1u, __ATOMIC_RELEASE,
                                           __HIP_MEMORY_SCOPE_AGENT);
                }
                // spin on quiet flag line (no RMW interference)
                while (__hip_atomic_load(flag, __ATOMIC_RELAXED,
                                         __HIP_MEMORY_SCOPE_AGENT) == 0)
                    __builtin_amdgcn_s_sleep(4);
                (void)__hip_atomic_load(flag, __ATOMIC_ACQUIRE,
                                        __HIP_MEMORY_SCOPE_AGENT);  // L1/L2 inv
            }
            __syncthreads();
        }
    }
}

extern "C" void kernel_launch(void* const* d_in, const int* in_sizes, int n_in,
                              void* d_out, int out_size, void* d_ws, size_t ws_size,
                              hipStream_t stream) {
    const float* enc_in = (const float*)d_in[0];
    const float* W_ih   = (const float*)d_in[1];
    const float* W_hh   = (const float*)d_in[2];
    const float* b_ih   = (const float*)d_in[3];
    const float* b_hh   = (const float*)d_in[4];
    float* out = (float*)d_out;

    char* ws = (char*)d_ws;
    unsigned short* Whh_bf = (unsigned short*)(ws);             // 6,291,456 B
    unsigned short* Wih_bf = (unsigned short*)(ws + 6291456);   //   589,824 B
    unsigned short* xT_bf  = (unsigned short*)(ws + 6881280);   // 4,816,896 B
    unsigned short* hbf0   = (unsigned short*)(ws + 11698176);  // 1,048,576 B
    unsigned short* hbf1   = (unsigned short*)(ws + 12746752);  // 1,048,576 B
    unsigned int*   bar    = (unsigned int*)(ws + 13795328);    //   125,440 B

    quantize_kernel<<<dim3(1024), dim3(256), 0, stream>>>(W_hh, W_ih, enc_in,
                                                          Whh_bf, Wih_bf, xT_bf, bar);

    void* args[] = {(void*)&Whh_bf, (void*)&Wih_bf, (void*)&xT_bf,
                    (void*)&b_ih, (void*)&b_hh,
                    (void*)&hbf0, (void*)&hbf1, (void*)&out, (void*)&bar};
    hipLaunchCooperativeKernel((const void*)gru_persist3,
                               dim3(256), dim3(512), args, 0, stream);
}